// Round 10
// baseline (8654.811 us; speedup 1.0000x reference)
//
#include <hip/hip_runtime.h>
#include <hip/hip_bf16.h>
#include <math.h>

// Problem dims: B=256, K(beams)=128, H=512, D=64, DEPTH=16
#define NB    256
#define NK    128
#define NH    512
#define ND    64
#define NDEPTH 16
#define BKROWS (NB*NK)          // 32768
#define TEMPD 20.0

typedef double d4 __attribute__((ext_vector_type(4)));

// ---------------- init
__global__ void k_init(const float* __restrict__ root, float* __restrict__ states,
                       double* __restrict__ scores, unsigned char* __restrict__ hist) {
    int idx = blockIdx.x * 256 + threadIdx.x;          // 0 .. 16,777,215
    states[idx] = root[idx & (NH - 1)];
    if (idx < BKROWS) scores[idx] = ((idx & (NK - 1)) == 0) ? 0.0 : -1e9;
    if (idx < BKROWS * NDEPTH) hist[idx] = 0;
}

// ---------------- K1: f64 MFMA logits GEMM + log-softmax + cand = score + logp
// grid 512, 256 threads = 4 waves. Block 64 rows x 64 cols; wave wv: rows wv*16..+15.
// T14 async-stage: next chunk's global loads issue before current chunk's MFMAs.
__global__ void __launch_bounds__(256, 4)
k_logits(const float* __restrict__ states,
         const float* __restrict__ Wl,      // [H][D] f32 row-major
         const float* __restrict__ bl,      // [D]
         const double* __restrict__ scores, // [B*K]
         double* __restrict__ cand)         // [B*K][D]
{
    __shared__ double wl[16][64];    // [kk][col] -- B-reads stride-1
    __shared__ double stT[16][67];   // [kk][r]   -- A-reads stride-1
    const int rowb = blockIdx.x * 64;
    const int t    = threadIdx.x;
    const int lane = t & 63;
    const int wv   = t >> 6;
    const int li   = lane & 15;
    const int kq   = lane >> 4;

    // per-thread staging coordinates (constant)
    const int wrow = t >> 5, wcp = t & 31;            // W: j*256+t -> row=idx>>5, cp=idx&31
    const int sr0 = t >> 3, scp = t & 7;              // S: r=idx>>3, cp=idx&7

    float2 wreg[2], sreg[2];
    #define LOGITS_LOAD(kc_) do {                                                        \
        wreg[0] = *(const float2*)&Wl[(size_t)((kc_) + wrow) * ND + 2 * wcp];            \
        wreg[1] = *(const float2*)&Wl[(size_t)((kc_) + 8 + wrow) * ND + 2 * wcp];        \
        sreg[0] = *(const float2*)&states[(size_t)(rowb + sr0) * NH + (kc_) + 2 * scp];  \
        sreg[1] = *(const float2*)&states[(size_t)(rowb + 32 + sr0) * NH + (kc_) + 2 * scp]; \
    } while (0)
    #define LOGITS_WRITE() do {                                                          \
        double2 d0; d0.x = (double)wreg[0].x; d0.y = (double)wreg[0].y;                  \
        *(double2*)&wl[wrow][2 * wcp] = d0;                                              \
        double2 d1; d1.x = (double)wreg[1].x; d1.y = (double)wreg[1].y;                  \
        *(double2*)&wl[8 + wrow][2 * wcp] = d1;                                          \
        stT[2 * scp][sr0]          = (double)sreg[0].x;                                  \
        stT[2 * scp + 1][sr0]      = (double)sreg[0].y;                                  \
        stT[2 * scp][32 + sr0]     = (double)sreg[1].x;                                  \
        stT[2 * scp + 1][32 + sr0] = (double)sreg[1].y;                                  \
    } while (0)

    d4 acc[4];
    #pragma unroll
    for (int c = 0; c < 4; ++c) { acc[c][0]=0.0; acc[c][1]=0.0; acc[c][2]=0.0; acc[c][3]=0.0; }

    LOGITS_LOAD(0); LOGITS_WRITE();
    __syncthreads();

    for (int kc = 0; kc < NH; kc += 16) {
        const bool more = (kc + 16) < NH;
        if (more) LOGITS_LOAD(kc + 16);     // issue loads; latency hides under MFMAs

        #pragma unroll
        for (int ks = 0; ks < 4; ++ks) {
            int kk = 4 * ks + kq;
            double a  = stT[kk][wv * 16 + li];
            double b0 = wl[kk][     li];
            double b1 = wl[kk][16 + li];
            double b2 = wl[kk][32 + li];
            double b3 = wl[kk][48 + li];
            acc[0] = __builtin_amdgcn_mfma_f64_16x16x4f64(a, b0, acc[0], 0, 0, 0);
            acc[1] = __builtin_amdgcn_mfma_f64_16x16x4f64(a, b1, acc[1], 0, 0, 0);
            acc[2] = __builtin_amdgcn_mfma_f64_16x16x4f64(a, b2, acc[2], 0, 0, 0);
            acc[3] = __builtin_amdgcn_mfma_f64_16x16x4f64(a, b3, acc[3], 0, 0, 0);
        }
        if (more) {
            __syncthreads();
            LOGITS_WRITE();
            __syncthreads();
        }
    }

    const double bd0 = (double)bl[li];
    const double bd1 = (double)bl[16 + li];
    const double bd2 = (double)bl[32 + li];
    const double bd3 = (double)bl[48 + li];
    #pragma unroll
    for (int n = 0; n < 4; ++n) {
        int row = rowb + wv * 16 + kq + 4 * n;
        double x0 = (acc[0][n] + bd0) / TEMPD;
        double x1 = (acc[1][n] + bd1) / TEMPD;
        double x2 = (acc[2][n] + bd2) / TEMPD;
        double x3 = (acc[3][n] + bd3) / TEMPD;
        double m = fmax(fmax(x0, x1), fmax(x2, x3));
        #pragma unroll
        for (int off = 1; off <= 8; off <<= 1) m = fmax(m, __shfl_xor(m, off, 64));
        double e = exp(x0 - m) + exp(x1 - m) + exp(x2 - m) + exp(x3 - m);
        #pragma unroll
        for (int off = 1; off <= 8; off <<= 1) e += __shfl_xor(e, off, 64);
        double ls = log(e);
        double sc = scores[row];
        cand[(size_t)row * ND +      li] = sc + x0 - m - ls;
        cand[(size_t)row * ND + 16 + li] = sc + x1 - m - ls;
        cand[(size_t)row * ND + 32 + li] = sc + x2 - m - ls;
        cand[(size_t)row * ND + 48 + li] = sc + x3 - m - ls;
    }
}

// ---------------- K2: per-batch top-128 of 8192 (value desc, index asc) + hist gather
// Single-wave selection from LDS; zero barriers inside the 128-iteration loop.
__global__ void __launch_bounds__(256)
k_topk(const double* __restrict__ cand,    // [B][8192]
       double* __restrict__ scores,
       int* __restrict__ parent, int* __restrict__ decs,
       const unsigned char* __restrict__ hist_in,
       unsigned char* __restrict__ hist_out,
       int tstep)
{
    extern __shared__ double smem[];
    double* L  = smem;                       // [128][65] flattened
    int*    sp = (int*)(smem + 128 * 65);    // [128]
    int*    sd = sp + NK;                    // [128]

    const int b = blockIdx.x;
    const int t = threadIdx.x;
    const double* cb = cand + (size_t)b * (NK * ND);

    #pragma unroll
    for (int j = 0; j < 32; ++j) {
        int i = j * 256 + t;
        L[(i >> 6) * 65 + (i & 63)] = cb[i];
    }
    __syncthreads();

    if (t < 64) {                            // wave 0 only; wave-synchronous
        const int lane = t;
        double mv = L[lane]; int mi = lane;
        for (int i = 1; i < 128; ++i) {
            double v = L[i * 65 + lane];
            if (v > mv) { mv = v; mi = i * 64 + lane; }
        }
        for (int it = 0; it < NK; ++it) {
            double m = mv; int idx = mi;
            #pragma unroll
            for (int off = 1; off <= 32; off <<= 1) {
                double m2 = __shfl_xor(m, off, 64);
                int    i2 = __shfl_xor(idx, off, 64);
                if (m2 > m || (m2 == m && i2 < idx)) { m = m2; idx = i2; }
            }
            const int wrow = idx >> 6, wcol = idx & 63;
            if (lane == 0) {
                scores[b * NK + it] = m;
                parent[b * NK + it] = wrow;
                decs  [b * NK + it] = wcol;
                sp[it] = wrow; sd[it] = wcol;
            }
            if (lane == wcol) L[wrow * 65 + wcol] = -INFINITY;
            double r0 = L[(2 * lane) * 65 + wcol];
            double r1 = L[(2 * lane + 1) * 65 + wcol];
            double rm; int ri;
            if (r1 > r0) { rm = r1; ri = (2 * lane + 1) * 64 + wcol; }
            else         { rm = r0; ri = (2 * lane) * 64 + wcol; }
            #pragma unroll
            for (int off = 1; off <= 32; off <<= 1) {
                double m2 = __shfl_xor(rm, off, 64);
                int    i2 = __shfl_xor(ri, off, 64);
                if (m2 > rm || (m2 == rm && i2 < ri)) { rm = m2; ri = i2; }
            }
            if (lane == wcol) { mv = rm; mi = ri; }
        }
    }
    __syncthreads();

    for (int i = t; i < NK * NDEPTH; i += 256) {
        int k = i >> 4, j = i & 15;
        hist_out[(b * NK + k) * NDEPTH + j] = (j == tstep) ? (unsigned char)sd[k]
                                            : hist_in[(b * NK + sp[k]) * NDEPTH + j];
    }
}

// ---------------- K3: f64 MFMA RNN step. new_states = tanh(states[parent]@W_hh + b_hh + emb[dec])
// grid (512, 4), 256 threads = 4 waves. Block 64 rows x 128 cols; wave (wm,wn): 32x64.
// wt[16][128]: B-reads stride-1; stT[16][67]: A-reads stride-1. T14 async-stage split.
__global__ void __launch_bounds__(256, 4)
k_rnn(const float* __restrict__ states_in,
      const float* __restrict__ Whh,   // [H][H] f32 row-major
      const float* __restrict__ bhh,
      const float* __restrict__ emb,   // [D][H]
      const int* __restrict__ parent, const int* __restrict__ decs,
      float* __restrict__ states_out)
{
    __shared__ double wt[16][128];   // [kk][col]
    __shared__ double stT[16][67];   // [kk][r]
    __shared__ int sp[64], sd[64];

    const int rowb = blockIdx.x * 64;
    const int cbk  = blockIdx.y;
    const int colb = cbk * 128;
    const int t    = threadIdx.x;
    const int lane = t & 63;
    const int li   = lane & 15;
    const int kq   = lane >> 4;     // 0..3
    const int wv   = t >> 6;
    const int wm   = wv >> 1;       // row-group (0,1)
    const int wn   = wv & 1;        // col-group (0,1)

    if (t < 64) { sp[t] = parent[rowb + t]; sd[t] = decs[rowb + t]; }
    __syncthreads();

    // staging coordinates (constant per thread)
    const int wrow = t >> 6, wcp = t & 63;    // W: 4 rows of j-steps: row = j*4 + (t>>6)
    const int sr0 = t >> 3, scp = t & 7;      // S: r = j*32 + (t>>3), cp = t&7
    int srow[2];
    srow[0] = ((rowb + sr0) >> 7) * NK + sp[sr0];
    srow[1] = ((rowb + 32 + sr0) >> 7) * NK + sp[32 + sr0];

    float2 wreg[4], sreg[2];
    #define RNN_LOAD(kc_) do {                                                               \
        wreg[0] = *(const float2*)&Whh[(size_t)((kc_) +      wrow) * NH + colb + 2 * wcp];   \
        wreg[1] = *(const float2*)&Whh[(size_t)((kc_) +  4 + wrow) * NH + colb + 2 * wcp];   \
        wreg[2] = *(const float2*)&Whh[(size_t)((kc_) +  8 + wrow) * NH + colb + 2 * wcp];   \
        wreg[3] = *(const float2*)&Whh[(size_t)((kc_) + 12 + wrow) * NH + colb + 2 * wcp];   \
        sreg[0] = *(const float2*)&states_in[(size_t)srow[0] * NH + (kc_) + 2 * scp];        \
        sreg[1] = *(const float2*)&states_in[(size_t)srow[1] * NH + (kc_) + 2 * scp];        \
    } while (0)
    #define RNN_WRITE() do {                                                                 \
        _Pragma("unroll")                                                                    \
        for (int j = 0; j < 4; ++j) {                                                        \
            double2 d; d.x = (double)wreg[j].x; d.y = (double)wreg[j].y;                     \
            *(double2*)&wt[j * 4 + wrow][2 * wcp] = d;                                       \
        }                                                                                    \
        stT[2 * scp][sr0]          = (double)sreg[0].x;                                      \
        stT[2 * scp + 1][sr0]      = (double)sreg[0].y;                                      \
        stT[2 * scp][32 + sr0]     = (double)sreg[1].x;                                      \
        stT[2 * scp + 1][32 + sr0] = (double)sreg[1].y;                                      \
    } while (0)

    d4 acc[2][4];
    #pragma unroll
    for (int i = 0; i < 2; ++i)
        #pragma unroll
        for (int j = 0; j < 4; ++j) { acc[i][j][0]=0.0; acc[i][j][1]=0.0; acc[i][j][2]=0.0; acc[i][j][3]=0.0; }

    RNN_LOAD(0); RNN_WRITE();
    __syncthreads();

    for (int kc = 0; kc < NH; kc += 16) {
        const bool more = (kc + 16) < NH;
        if (more) RNN_LOAD(kc + 16);        // issue loads; latency hides under MFMAs

        #pragma unroll
        for (int ks = 0; ks < 4; ++ks) {
            int kk = 4 * ks + kq;
            double a0 = stT[kk][wm * 32 + li];
            double a1 = stT[kk][wm * 32 + 16 + li];
            double b0 = wt[kk][wn * 64 +      li];
            double b1 = wt[kk][wn * 64 + 16 + li];
            double b2 = wt[kk][wn * 64 + 32 + li];
            double b3 = wt[kk][wn * 64 + 48 + li];
            acc[0][0] = __builtin_amdgcn_mfma_f64_16x16x4f64(a0, b0, acc[0][0], 0, 0, 0);
            acc[0][1] = __builtin_amdgcn_mfma_f64_16x16x4f64(a0, b1, acc[0][1], 0, 0, 0);
            acc[0][2] = __builtin_amdgcn_mfma_f64_16x16x4f64(a0, b2, acc[0][2], 0, 0, 0);
            acc[0][3] = __builtin_amdgcn_mfma_f64_16x16x4f64(a0, b3, acc[0][3], 0, 0, 0);
            acc[1][0] = __builtin_amdgcn_mfma_f64_16x16x4f64(a1, b0, acc[1][0], 0, 0, 0);
            acc[1][1] = __builtin_amdgcn_mfma_f64_16x16x4f64(a1, b1, acc[1][1], 0, 0, 0);
            acc[1][2] = __builtin_amdgcn_mfma_f64_16x16x4f64(a1, b2, acc[1][2], 0, 0, 0);
            acc[1][3] = __builtin_amdgcn_mfma_f64_16x16x4f64(a1, b3, acc[1][3], 0, 0, 0);
        }
        if (more) {
            __syncthreads();
            RNN_WRITE();
            __syncthreads();
        }
    }

    // epilogue: D[i][j]: j = lane&15, i = (lane>>4) + 4n (verified L1)
    #pragma unroll
    for (int ct = 0; ct < 4; ++ct) {
        int col = colb + wn * 64 + ct * 16 + li;
        double bb = (double)bhh[col];
        #pragma unroll
        for (int rt = 0; rt < 2; ++rt) {
            #pragma unroll
            for (int n = 0; n < 4; ++n) {
                int rL = wm * 32 + rt * 16 + kq + 4 * n;
                double e = (double)emb[(size_t)sd[rL] * NH + col];
                double z = acc[rt][ct][n] + bb + e;
                states_out[(size_t)(rowb + rL) * NH + col] = (float)tanh(z);
            }
        }
    }
}

// ---------------- finalize: d_out = [hist as float (524288), scores as float (32768)]
__global__ void k_final(const unsigned char* __restrict__ hist,
                        const double* __restrict__ scores,
                        float* __restrict__ out)
{
    int i = blockIdx.x * 256 + threadIdx.x;
    const int nh = BKROWS * NDEPTH;      // 524288
    if (i < nh) out[i] = (float)hist[i];
    else if (i < nh + BKROWS) out[i] = (float)scores[i - nh];
}

extern "C" void kernel_launch(void* const* d_in, const int* in_sizes, int n_in,
                              void* d_out, int out_size, void* d_ws, size_t ws_size,
                              hipStream_t stream) {
    // inputs: env(unused), root_state, W_logits, b_logits, W_hh, b_hh, emb, beams(=128)
    const float* root = (const float*)d_in[1];
    const float* Wl   = (const float*)d_in[2];
    const float* bl   = (const float*)d_in[3];
    const float* Whh  = (const float*)d_in[4];
    const float* bhh  = (const float*)d_in[5];
    const float* emb  = (const float*)d_in[6];

    char* ws = (char*)d_ws;
    double* cand         = (double*)(ws + 0);             // 16,777,216
    double* scores       = (double*)(ws + 16777216);      //    262,144
    float*  sA           = (float*)(ws + 17039360);       // 67,108,864
    float*  sB           = (float*)(ws + 84148224);       // 67,108,864
    int*    parent       = (int*)(ws + 151257088);        //    131,072
    int*    decs         = (int*)(ws + 151388160);        //    131,072
    unsigned char* hA    = (unsigned char*)(ws + 151519232); // 524,288
    unsigned char* hB    = (unsigned char*)(ws + 152043520); // 524,288
    // total 152,567,808 bytes (<= proven 155,713,536)

    k_init<<<65536, 256, 0, stream>>>(root, sA, scores, hA);

    float* scur = sA; float* snxt = sB;
    unsigned char* hcur = hA; unsigned char* hnxt = hB;
    for (int t = 0; t < NDEPTH; ++t) {
        k_logits<<<512, 256, 0, stream>>>(scur, Wl, bl, scores, cand);
        k_topk<<<256, 256, 67584, stream>>>(cand, scores, parent, decs, hcur, hnxt, t);
        k_rnn<<<dim3(512, 4), 256, 0, stream>>>(scur, Whh, bhh, emb, parent, decs, snxt);
        { float* tmp = scur; scur = snxt; snxt = tmp; }
        { unsigned char* tmp = hcur; hcur = hnxt; hnxt = tmp; }
    }

    k_final<<<2176, 256, 0, stream>>>(hcur, scores, (float*)d_out);
}